// Round 2
// baseline (19679.956 us; speedup 1.0000x reference)
//
#include <hip/hip_runtime.h>
#include <hip/hip_fp16.h>

// Persistent fused GRU + value head for MI355X (gfx950).
// T=512,B=256,I=64,H=512. Grid = 256 wgs = 16 batch groups x 16 hidden slices.
// Weights stationary in VGPRs as MFMA B-fragments. h exchanged per step as f16
// via cache-bypass (sc0 sc1) 16B loads/stores + per-group monotonic counter.

#define T_  512
#define B_  256
#define I_  64
#define H_  512
#define NBG 16   // batch groups
#define NHS 16   // hidden slices per group (sync fan-in)
#define BT  16   // batch per group (MFMA M)
#define HS  32   // hidden units per slice
#define NCOL 96  // 3*HS preact columns [r|z|n]
#define BLOCK 512
#define NMW 6    // waves 0..5 do MFMA (6 waves x 16 cols = 96)
#define CTR_STRIDE 32  // uints -> 128 B between group counters (kill line sharing)

typedef _Float16 f16;
typedef _Float16 f16x8 __attribute__((ext_vector_type(8)));
typedef float    f32x4 __attribute__((ext_vector_type(4)));

__device__ __forceinline__ float sigmoid_f(float x) { return 1.f / (1.f + __expf(-x)); }
__device__ __forceinline__ float tanh_f(float x) {
    float e2 = __expf(2.f * x);          // inf-safe
    return 1.f - 2.f / (e2 + 1.f);
}

__global__ __launch_bounds__(BLOCK) void gru_persistent(
    const float* __restrict__ X, const float* __restrict__ Wih,
    const float* __restrict__ Whh, const float* __restrict__ bih,
    const float* __restrict__ bhh, const float* __restrict__ vw,
    const float* __restrict__ bias, float* __restrict__ Vout,
    f16* __restrict__ hbuf, unsigned int* __restrict__ ctr)
{
    const int blk  = blockIdx.x;
    const int g    = (blk & 7) * 2 + (blk >> 7);   // group shares blk%8 -> same XCD (heuristic)
    const int j    = (blk >> 3) & 15;
    const int b0   = g * BT;
    const int tid  = threadIdx.x;
    const int wv   = tid >> 6;
    const int lane = tid & 63;
    const int quad = lane >> 4;
    const int mrow = lane & 15;

    __shared__ __align__(16) f16 sh_h[BT][H_ + 8];   // +8 halves pad, rows stay 16B-aligned
    __shared__ __align__(16) f16 sh_x[BT][I_ + 8];
    __shared__ float sh_hh[2][BT][HS];               // fp32 own-slice h ping-pong (z*h anchor)
    __shared__ float sh_Ph[BT][NCOL + 4];
    __shared__ float sh_Pin[BT][NCOL + 4];
    __shared__ __align__(16) f16 sh_hnew16[BT][HS];
    __shared__ float sh_bih[NCOL], sh_bhh[NCOL], sh_vw[HS];

    // ---- stationary MFMA B-fragments (16x16x32_f16: B[k][n], n=lane&15, k=quad*8+e) ----
    const bool mf   = (wv < NMW);
    const int  ncol = mf ? (wv * 16 + mrow) : mrow;            // clamped (unused) for waves 6,7
    const int  grow = (ncol >> 5) * H_ + HS * j + (ncol & 31); // row in (3H,*) weights

    f16x8 wfrag[16];
    #pragma unroll
    for (int kt = 0; kt < 16; kt++) {
        const float* src = Whh + (size_t)grow * H_ + kt * 32 + quad * 8;
        #pragma unroll
        for (int e = 0; e < 8; e++) wfrag[kt][e] = (f16)src[e];
    }
    f16x8 wfragX[2];
    #pragma unroll
    for (int kt = 0; kt < 2; kt++) {
        const float* src = Wih + (size_t)grow * I_ + kt * 32 + quad * 8;
        #pragma unroll
        for (int e = 0; e < 8; e++) wfragX[kt][e] = (f16)src[e];
    }

    if (tid < NCOL) {
        int gr = (tid >> 5) * H_ + HS * j + (tid & 31);
        sh_bih[tid] = bih[gr];
        sh_bhh[tid] = bhh[gr];
    } else if (tid < NCOL + HS) {
        sh_vw[tid - NCOL] = vw[HS * j + (tid - NCOL)];
    }
    sh_hh[1][tid >> 5][tid & 31] = 0.f;   // t=0 reads ping buffer 1
    const float bias0 = bias[0];
    __syncthreads();

    unsigned int* myctr = &ctr[g * CTR_STRIDE];

    #pragma unroll 1
    for (int t = 0; t < T_; t++) {
        // ---- 0. X_t staging (cached, h-independent): overlap with the spin ----
        if (tid < 256) {
            int bb = tid >> 4, i4 = (tid & 15) * 4;
            const float4 xv = *(const float4*)&X[(size_t)t * (B_ * I_) + (size_t)(b0 + bb) * I_ + i4];
            f16* dst = &sh_x[bb][i4];
            dst[0] = (f16)xv.x; dst[1] = (f16)xv.y; dst[2] = (f16)xv.z; dst[3] = (f16)xv.w;
        }

        // ---- 1. per-wave spin: lane 0 polls group counter ----
        if (t > 0 && lane == 0) {
            const unsigned target = (unsigned)(NHS * t);
            while (__hip_atomic_load(myctr, __ATOMIC_ACQUIRE, __HIP_MEMORY_SCOPE_AGENT) < target)
                __builtin_amdgcn_s_sleep(1);
        }

        // ---- 2. coherent bypass read of h_{t-1} (f16): 2 x 16B chunks/thread ----
        {
            const f16* hprev = hbuf + (size_t)((t & 1) ^ 1) * (B_ * H_);
            const int c0 = tid, c1 = tid + 512;   // 1024 chunks of 8 halves
            const f16* p0 = hprev + (size_t)(b0 + (c0 >> 6)) * H_ + (c0 & 63) * 8;
            const f16* p1 = hprev + (size_t)(b0 + (c1 >> 6)) * H_ + (c1 & 63) * 8;
            f16x8 v0, v1;
            asm volatile(
                "global_load_dwordx4 %0, %2, off sc0 sc1\n\t"
                "global_load_dwordx4 %1, %3, off sc0 sc1\n\t"
                "s_waitcnt vmcnt(0)"
                : "=&v"(v0), "=&v"(v1)
                : "v"(p0), "v"(p1)
                : "memory");
            *(f16x8*)&sh_h[c0 >> 6][(c0 & 63) * 8] = v0;
            *(f16x8*)&sh_h[c1 >> 6][(c1 & 63) * 8] = v1;
        }
        __syncthreads();

        // ---- 3. MFMA preacts: h @ Whh_slice^T, x @ Wih_slice^T ----
        if (mf) {
            f32x4 acch  = {0.f, 0.f, 0.f, 0.f};
            f32x4 accin = {0.f, 0.f, 0.f, 0.f};
            #pragma unroll
            for (int kt = 0; kt < 16; kt++) {
                f16x8 a = *(const f16x8*)&sh_h[mrow][kt * 32 + quad * 8];
                acch = __builtin_amdgcn_mfma_f32_16x16x32_f16(a, wfrag[kt], acch, 0, 0, 0);
            }
            #pragma unroll
            for (int kt = 0; kt < 2; kt++) {
                f16x8 a = *(const f16x8*)&sh_x[mrow][kt * 32 + quad * 8];
                accin = __builtin_amdgcn_mfma_f32_16x16x32_f16(a, wfragX[kt], accin, 0, 0, 0);
            }
            #pragma unroll
            for (int r = 0; r < 4; r++) {         // C/D: col=lane&15, row=quad*4+r
                int m = quad * 4 + r;
                sh_Ph[m][ncol]  = acch[r];
                sh_Pin[m][ncol] = accin[r];
            }
        }
        __syncthreads();

        // ---- 4. gates (fp32): exactly one element per thread ----
        {
            const int bb = tid >> 5, u = tid & 31;
            float pr   = sh_Pin[bb][u]      + sh_bih[u]      + sh_Ph[bb][u]      + sh_bhh[u];
            float pz   = sh_Pin[bb][32 + u] + sh_bih[32 + u] + sh_Ph[bb][32 + u] + sh_bhh[32 + u];
            float pnin = sh_Pin[bb][64 + u] + sh_bih[64 + u];
            float pnh  = sh_Ph[bb][64 + u]  + sh_bhh[64 + u];
            float r = sigmoid_f(pr);
            float z = sigmoid_f(pz);
            float n = tanh_f(pnin + r * pnh);
            float hn = (1.f - z) * n + z * sh_hh[(t & 1) ^ 1][bb][u];
            sh_hh[t & 1][bb][u] = hn;
            sh_hnew16[bb][u] = (f16)hn;
        }
        __syncthreads();

        // ---- 5. publish h_t slice (f16 bypass stores, wave 0), drain, signal ----
        if (tid < 64) {
            const int bb = tid >> 2, c = tid & 3;  // 16 rows x 4 chunks of 8 halves
            f16x8 v = *(const f16x8*)&sh_hnew16[bb][c * 8];
            f16* p = hbuf + (size_t)(t & 1) * (B_ * H_) + (size_t)(b0 + bb) * H_ + HS * j + c * 8;
            asm volatile(
                "global_store_dwordx4 %0, %1, off sc0 sc1\n\t"
                "s_waitcnt vmcnt(0)"
                :: "v"(p), "v"(v) : "memory");
        }
        if (tid == 0)   // same wave as the stores: its vmcnt(0) drained them
            __hip_atomic_fetch_add(myctr, 1u, __ATOMIC_RELEASE, __HIP_MEMORY_SCOPE_AGENT);

        // ---- 6. value head partial (off critical path, after signal) ----
        if (tid < BT) {
            float s = (j == 0) ? bias0 : 0.f;
            #pragma unroll
            for (int u = 0; u < HS; u++) s += sh_hh[t & 1][tid][u] * sh_vw[u];
            atomicAdd(&Vout[(size_t)t * B_ + b0 + tid], s);
        }
    }
}

extern "C" void kernel_launch(void* const* d_in, const int* in_sizes, int n_in,
                              void* d_out, int out_size, void* d_ws, size_t ws_size,
                              hipStream_t stream) {
    const float* X    = (const float*)d_in[0];
    const float* Wih  = (const float*)d_in[1];
    const float* Whh  = (const float*)d_in[2];
    const float* bih  = (const float*)d_in[3];
    const float* bhh  = (const float*)d_in[4];
    const float* vw   = (const float*)d_in[5];
    const float* bias = (const float*)d_in[6];
    float* Vout = (float*)d_out;

    // ws layout: ping-pong f16 h buffers (2 x B*H), then padded group counters
    f16* hbuf = (f16*)d_ws;
    size_t hbytes = (size_t)2 * B_ * H_ * sizeof(f16);
    unsigned int* ctr = (unsigned int*)((char*)d_ws + hbytes);

    hipMemsetAsync(d_ws, 0, hbytes + NBG * CTR_STRIDE * sizeof(unsigned int), stream);
    hipMemsetAsync(d_out, 0, (size_t)out_size * sizeof(float), stream);

    gru_persistent<<<256, BLOCK, 0, stream>>>(X, Wih, Whh, bih, bhh, vw, bias, Vout, hbuf, ctr);
}

// Round 3
// 1733.150 us; speedup vs baseline: 11.3550x; 11.3550x over previous
//
#include <hip/hip_runtime.h>
#include <hip/hip_fp16.h>

// Persistent fused GRU + value head, MI355X (gfx950).
// T=512,B=256,I=64,H=512. 256 blocks = 16 batch groups x 16 hidden slices, 1 block/CU.
// Weights stationary in VGPRs (3 fat MFMA waves x 32 cols). h exchanged per step as f16:
// publishers use relaxed-atomic half2 write-through stores; readers load A-fragments
// directly from the coherence point (sc0 sc1), no cache invalidates anywhere.
// Sync: per-group padded monotonic counter, relaxed polls, release via barrier-drained RMW.

#define T_  512
#define B_  256
#define I_  64
#define H_  512
#define NBG 16
#define NHS 16
#define BT  16
#define HS  32
#define NCOL 96
#define BLOCK 256
#define NMW 3          // waves 0..2 do MFMA, 32 cols each
#define CTR_STRIDE 32  // uints: 128B between group counters

typedef _Float16 f16;
typedef _Float16 f16x8 __attribute__((ext_vector_type(8)));
typedef float    f32x4 __attribute__((ext_vector_type(4)));

__device__ __forceinline__ float sigmoid_f(float x) { return 1.f / (1.f + __expf(-x)); }
__device__ __forceinline__ float tanh_f(float x) {
    float e2 = __expf(2.f * x);
    return 1.f - 2.f / (e2 + 1.f);
}

__global__ __launch_bounds__(BLOCK, 1) void gru_persistent(
    const float* __restrict__ X, const float* __restrict__ Wih,
    const float* __restrict__ Whh, const float* __restrict__ bih,
    const float* __restrict__ bhh, const float* __restrict__ vw,
    const float* __restrict__ bias, float* __restrict__ Vout,
    f16* __restrict__ hbuf, unsigned int* __restrict__ ctr,
    float* __restrict__ part, const int use_part)
{
    const int blk  = blockIdx.x;
    const int g    = (blk & 7) * 2 + (blk >> 7);   // group members share blk%8 (same-XCD heuristic)
    const int j    = (blk >> 3) & 15;
    const int b0   = g * BT;
    const int tid  = threadIdx.x;
    const int wv   = tid >> 6;
    const int lane = tid & 63;
    const int quad = lane >> 4;
    const int mrow = lane & 15;

    __shared__ __align__(16) f16 sh_x[BT][I_ + 8];   // X_t as f16 (stride 144B, 16B-aligned)
    __shared__ float sh_hh[2][BT][HS];               // fp32 own-slice h ping-pong (z*h anchor)
    __shared__ float sh_Ph[BT][NCOL + 4];            // hidden-proj preacts
    __shared__ float sh_Pin[BT][NCOL + 4];           // input-proj preacts
    __shared__ float sh_brz[64];                     // bih+bhh folded for r,z
    __shared__ float sh_bin[HS], sh_bhn[HS], sh_vw[HS];

    // ---- stationary B-fragments: 2 column-tiles per MFMA wave ----
    const bool mf = (wv < NMW);
    f16x8 wfrag[16][2];   // [kt][tile]
    f16x8 wfragX[2][2];
    #pragma unroll
    for (int tt = 0; tt < 2; tt++) {
        const int ncol = (mf ? wv : 0) * 32 + tt * 16 + mrow;
        const int grow = (ncol >> 5) * H_ + HS * j + (ncol & 31);
        #pragma unroll
        for (int kt = 0; kt < 16; kt++) {
            const float* src = Whh + (size_t)grow * H_ + kt * 32 + quad * 8;
            #pragma unroll
            for (int e = 0; e < 8; e++) wfrag[kt][tt][e] = (f16)src[e];
        }
        #pragma unroll
        for (int kt = 0; kt < 2; kt++) {
            const float* src = Wih + (size_t)grow * I_ + kt * 32 + quad * 8;
            #pragma unroll
            for (int e = 0; e < 8; e++) wfragX[kt][tt][e] = (f16)src[e];
        }
    }

    if (tid < 64) {                                   // r,z bias fold
        int row = (tid >> 5) * H_ + HS * j + (tid & 31);
        sh_brz[tid] = bih[row] + bhh[row];
    } else if (tid < 96) {
        int u = tid - 64, row = 2 * H_ + HS * j + u;
        sh_bin[u] = bih[row]; sh_bhn[u] = bhh[row];
    } else if (tid < 128) {
        sh_vw[tid - 96] = vw[HS * j + (tid - 96)];
    }
    sh_hh[1][tid >> 4][(tid & 15) * 2]     = 0.f;     // t=0 anchor = 0
    sh_hh[1][tid >> 4][(tid & 15) * 2 + 1] = 0.f;
    {   // stage X_0
        int bb = tid >> 4, i4 = (tid & 15) * 4;
        const float4 xv = *(const float4*)&X[(size_t)(b0 + bb) * I_ + i4];
        f16* dst = &sh_x[bb][i4];
        dst[0] = (f16)xv.x; dst[1] = (f16)xv.y; dst[2] = (f16)xv.z; dst[3] = (f16)xv.w;
    }
    const float bias0 = bias[0];
    unsigned int* myctr = &ctr[g * CTR_STRIDE];
    __syncthreads();

    #pragma unroll 1
    for (int t = 0; t < T_; t++) {
        if (mf) {
            // ---- 1. relaxed spin (lane 0 of each MFMA wave; no invalidates) ----
            if (t > 0 && lane == 0) {
                const unsigned target = (unsigned)(NHS * t);
                while (__hip_atomic_load(myctr, __ATOMIC_RELAXED, __HIP_MEMORY_SCOPE_AGENT) < target)
                    __builtin_amdgcn_s_sleep(1);
            }

            // ---- 2. A-fragments straight from coherence point: 16 x 16B, one round trip ----
            f16x8 afr[16];
            const f16* abase = hbuf + (size_t)((t & 1) ^ 1) * (B_ * H_)
                             + (size_t)(b0 + mrow) * H_ + quad * 8;
            asm volatile(
                "global_load_dwordx4 %0, %16, off sc0 sc1\n\t"
                "global_load_dwordx4 %1, %16, off offset:64 sc0 sc1\n\t"
                "global_load_dwordx4 %2, %16, off offset:128 sc0 sc1\n\t"
                "global_load_dwordx4 %3, %16, off offset:192 sc0 sc1\n\t"
                "global_load_dwordx4 %4, %16, off offset:256 sc0 sc1\n\t"
                "global_load_dwordx4 %5, %16, off offset:320 sc0 sc1\n\t"
                "global_load_dwordx4 %6, %16, off offset:384 sc0 sc1\n\t"
                "global_load_dwordx4 %7, %16, off offset:448 sc0 sc1\n\t"
                "global_load_dwordx4 %8, %16, off offset:512 sc0 sc1\n\t"
                "global_load_dwordx4 %9, %16, off offset:576 sc0 sc1\n\t"
                "global_load_dwordx4 %10, %16, off offset:640 sc0 sc1\n\t"
                "global_load_dwordx4 %11, %16, off offset:704 sc0 sc1\n\t"
                "global_load_dwordx4 %12, %16, off offset:768 sc0 sc1\n\t"
                "global_load_dwordx4 %13, %16, off offset:832 sc0 sc1\n\t"
                "global_load_dwordx4 %14, %16, off offset:896 sc0 sc1\n\t"
                "global_load_dwordx4 %15, %16, off offset:960 sc0 sc1\n\t"
                "s_waitcnt vmcnt(0)"
                : "=&v"(afr[0]), "=&v"(afr[1]), "=&v"(afr[2]), "=&v"(afr[3]),
                  "=&v"(afr[4]), "=&v"(afr[5]), "=&v"(afr[6]), "=&v"(afr[7]),
                  "=&v"(afr[8]), "=&v"(afr[9]), "=&v"(afr[10]), "=&v"(afr[11]),
                  "=&v"(afr[12]), "=&v"(afr[13]), "=&v"(afr[14]), "=&v"(afr[15])
                : "v"(abase)
                : "memory");

            // ---- 3. MFMA: 2 column-tiles share each A-fragment ----
            f32x4 acc_h[2] = {{0.f,0.f,0.f,0.f},{0.f,0.f,0.f,0.f}};
            f32x4 acc_i[2] = {{0.f,0.f,0.f,0.f},{0.f,0.f,0.f,0.f}};
            #pragma unroll
            for (int kt = 0; kt < 16; kt++) {
                acc_h[0] = __builtin_amdgcn_mfma_f32_16x16x32_f16(afr[kt], wfrag[kt][0], acc_h[0], 0, 0, 0);
                acc_h[1] = __builtin_amdgcn_mfma_f32_16x16x32_f16(afr[kt], wfrag[kt][1], acc_h[1], 0, 0, 0);
            }
            #pragma unroll
            for (int kt = 0; kt < 2; kt++) {
                f16x8 ax = *(const f16x8*)&sh_x[mrow][kt * 32 + quad * 8];
                acc_i[0] = __builtin_amdgcn_mfma_f32_16x16x32_f16(ax, wfragX[kt][0], acc_i[0], 0, 0, 0);
                acc_i[1] = __builtin_amdgcn_mfma_f32_16x16x32_f16(ax, wfragX[kt][1], acc_i[1], 0, 0, 0);
            }
            #pragma unroll
            for (int tt = 0; tt < 2; tt++) {
                const int c = wv * 32 + tt * 16 + mrow;
                #pragma unroll
                for (int r = 0; r < 4; r++) {          // C/D: col=lane&15, row=quad*4+r
                    const int m = quad * 4 + r;
                    sh_Ph[m][c]  = acc_h[tt][r];
                    sh_Pin[m][c] = acc_i[tt][r];
                }
            }
        }
        __syncthreads();   // B2: preacts ready

        // ---- 4. gates (2 elems/thread), publish half2, stage X_{t+1} ----
        {
            const int bb = tid >> 4, u0 = (tid & 15) * 2;
            float2 pin_r = *(const float2*)&sh_Pin[bb][u0];
            float2 ph_r  = *(const float2*)&sh_Ph[bb][u0];
            float2 pin_z = *(const float2*)&sh_Pin[bb][32 + u0];
            float2 ph_z  = *(const float2*)&sh_Ph[bb][32 + u0];
            float2 pin_n = *(const float2*)&sh_Pin[bb][64 + u0];
            float2 ph_n  = *(const float2*)&sh_Ph[bb][64 + u0];
            float2 brz_r = *(const float2*)&sh_brz[u0];
            float2 brz_z = *(const float2*)&sh_brz[32 + u0];
            float2 bn_i  = *(const float2*)&sh_bin[u0];
            float2 bn_h  = *(const float2*)&sh_bhn[u0];
            float2 hold  = *(const float2*)&sh_hh[(t & 1) ^ 1][bb][u0];

            float r0 = sigmoid_f(pin_r.x + ph_r.x + brz_r.x);
            float r1 = sigmoid_f(pin_r.y + ph_r.y + brz_r.y);
            float z0 = sigmoid_f(pin_z.x + ph_z.x + brz_z.x);
            float z1 = sigmoid_f(pin_z.y + ph_z.y + brz_z.y);
            float n0 = tanh_f(pin_n.x + bn_i.x + r0 * (ph_n.x + bn_h.x));
            float n1 = tanh_f(pin_n.y + bn_i.y + r1 * (ph_n.y + bn_h.y));
            float h0 = (1.f - z0) * n0 + z0 * hold.x;
            float h1 = (1.f - z1) * n1 + z1 * hold.y;

            *(float2*)&sh_hh[t & 1][bb][u0] = make_float2(h0, h1);
            union { f16 h2[2]; unsigned int u32; } pk;
            pk.h2[0] = (f16)h0; pk.h2[1] = (f16)h1;
            f16* hp = hbuf + (size_t)(t & 1) * (B_ * H_) + (size_t)(b0 + bb) * H_ + HS * j + u0;
            __hip_atomic_store((unsigned int*)hp, pk.u32,
                               __ATOMIC_RELAXED, __HIP_MEMORY_SCOPE_AGENT);

            if (t + 1 < T_) {   // stage next X (read-only, cached; barrier-protected by B3)
                int i4 = (tid & 15) * 4;
                const float4 xv = *(const float4*)&X[(size_t)(t + 1) * (B_ * I_)
                                                     + (size_t)(b0 + bb) * I_ + i4];
                f16* dst = &sh_x[bb][i4];
                dst[0] = (f16)xv.x; dst[1] = (f16)xv.y; dst[2] = (f16)xv.z; dst[3] = (f16)xv.w;
            }
        }
        __syncthreads();   // B3: every wave's h-stores drained (vmcnt) before signal

        if (tid == 0)
            __hip_atomic_fetch_add(myctr, 1u, __ATOMIC_RELAXED, __HIP_MEMORY_SCOPE_AGENT);

        // ---- 5. value head partial (exclusive region, off critical path) ----
        if (tid < BT) {
            float s = 0.f;
            #pragma unroll
            for (int u = 0; u < HS; u++) s += sh_hh[t & 1][tid][u] * sh_vw[u];
            if (use_part) part[((size_t)j * T_ + t) * B_ + b0 + tid] = s;
            else          atomicAdd(&Vout[(size_t)t * B_ + b0 + tid], s + (j == 0 ? bias0 : 0.f));
        }
    }
}

__global__ __launch_bounds__(256) void value_reduce(
    const float* __restrict__ part, const float* __restrict__ bias,
    float* __restrict__ Vout)
{
    const int i = blockIdx.x * 256 + threadIdx.x;   // i < T_*B_
    float s = bias[0];
    #pragma unroll
    for (int jj = 0; jj < NHS; jj++) s += part[(size_t)jj * (T_ * B_) + i];
    Vout[i] = s;
}

extern "C" void kernel_launch(void* const* d_in, const int* in_sizes, int n_in,
                              void* d_out, int out_size, void* d_ws, size_t ws_size,
                              hipStream_t stream) {
    const float* X    = (const float*)d_in[0];
    const float* Wih  = (const float*)d_in[1];
    const float* Whh  = (const float*)d_in[2];
    const float* bih  = (const float*)d_in[3];
    const float* bhh  = (const float*)d_in[4];
    const float* vw   = (const float*)d_in[5];
    const float* bias = (const float*)d_in[6];
    float* Vout = (float*)d_out;

    f16* hbuf = (f16*)d_ws;
    const size_t hbytes   = (size_t)2 * B_ * H_ * sizeof(f16);          // 512 KB
    const size_t ctrbytes = (size_t)NBG * CTR_STRIDE * sizeof(unsigned);// 2 KB
    unsigned int* ctr = (unsigned int*)((char*)d_ws + hbytes);
    float* part = (float*)((char*)d_ws + hbytes + ctrbytes);
    const size_t partbytes = (size_t)NHS * T_ * B_ * sizeof(float);     // 8 MB
    const int use_part = (ws_size >= hbytes + ctrbytes + partbytes) ? 1 : 0;

    hipMemsetAsync(d_ws, 0, hbytes + ctrbytes, stream);
    if (!use_part)
        hipMemsetAsync(d_out, 0, (size_t)out_size * sizeof(float), stream);

    gru_persistent<<<256, BLOCK, 0, stream>>>(X, Wih, Whh, bih, bhh, vw, bias,
                                              Vout, hbuf, ctr, part, use_part);
    if (use_part)
        value_reduce<<<(T_ * B_) / 256, 256, 0, stream>>>(part, bias, Vout);
}

// Round 4
// 1692.417 us; speedup vs baseline: 11.6283x; 1.0241x over previous
//
#include <hip/hip_runtime.h>
#include <hip/hip_fp16.h>

// Persistent fused GRU + value head, MI355X (gfx950).
// T=512,B=256,I=64,H=512. 256 blocks = 16 batch groups x 16 hidden slices.
// Each block: 2 MFMA waves (16 units each, all 3 gates -> gates fully in registers,
// zero preact LDS, zero tail barriers) + 1 service wave (X prefetch).
// h exchanged as f16 through the device coherence point (sc0 sc1); per-group
// monotonic counter, relaxed polls, per-wave signal after own vmcnt drain.

#define T_  512
#define B_  256
#define I_  64
#define H_  512
#define NBG 16
#define NHS 16                 // blocks per batch group
#define BT  16                 // batch rows per group (MFMA M)
#define HS  32                 // hidden units per block
#define BLOCK 192
#define NMW 2                  // MFMA waves per block
#define SIGS (NHS * NMW)       // signals per step per group = 32
#define NSL (NHS * NMW)        // value-head slices
#define CTR_STRIDE 32          // 128 B between group counters

typedef _Float16 f16;
typedef _Float16 f16x8 __attribute__((ext_vector_type(8)));
typedef float    f32x4 __attribute__((ext_vector_type(4)));

__device__ __forceinline__ float sigmoid_f(float x) { return 1.f / (1.f + __expf(-x)); }
__device__ __forceinline__ float tanh_f(float x) {
    float e2 = __expf(2.f * x);
    return 1.f - 2.f / (e2 + 1.f);
}

__global__ __launch_bounds__(BLOCK, 1) void gru_persistent(
    const float* __restrict__ X, const float* __restrict__ Wih,
    const float* __restrict__ Whh, const float* __restrict__ bih,
    const float* __restrict__ bhh, const float* __restrict__ vw,
    const float* __restrict__ bias, float* __restrict__ Vout,
    f16* __restrict__ hbuf, unsigned int* __restrict__ ctr,
    float* __restrict__ part, const int use_part)
{
    const int blk  = blockIdx.x;
    const int g    = (blk & 7) * 2 + (blk >> 7);   // group members share blk%8 (XCD heuristic)
    const int j    = (blk >> 3) & 15;
    const int b0   = g * BT;
    const int tid  = threadIdx.x;
    const int wv   = tid >> 6;
    const int lane = tid & 63;
    const int quad = lane >> 4;
    const int mrow = lane & 15;

    __shared__ __align__(16) f16 sh_x[2][BT][I_ + 8];   // ping-pong X_t (f16), padded
    unsigned int* myctr = &ctr[g * CTR_STRIDE];
    const float bias0 = bias[0];

    if (wv < NMW) {
        // ================= MFMA waves: 16 units each, gates r|z|n =================
        // B-frag (16x16x32_f16): B[k][n], n=lane&15 -> unit, k=quad*8+e.
        f16x8 wh[3][16];   // Whh fragments per gate, K=512
        f16x8 wx[3][2];    // Wih fragments per gate, K=64
        const int ubase = HS * j + wv * 16 + mrow;   // global unit row (r-gate)
        #pragma unroll
        for (int g3 = 0; g3 < 3; g3++) {
            const size_t grow = (size_t)(g3 * H_ + ubase);
            #pragma unroll
            for (int kt = 0; kt < 16; kt++) {
                const float* src = Whh + grow * H_ + kt * 32 + quad * 8;
                #pragma unroll
                for (int e = 0; e < 8; e++) wh[g3][kt][e] = (f16)src[e];
            }
            #pragma unroll
            for (int kt = 0; kt < 2; kt++) {
                const float* src = Wih + grow * I_ + kt * 32 + quad * 8;
                #pragma unroll
                for (int e = 0; e < 8; e++) wx[g3][kt][e] = (f16)src[e];
            }
        }
        const float b_r  = bih[ubase] + bhh[ubase];
        const float b_z  = bih[H_ + ubase] + bhh[H_ + ubase];
        const float b_ni = bih[2 * H_ + ubase];
        const float b_nh = bhh[2 * H_ + ubase];
        const float vw_u = vw[ubase];
        float hprev[4] = {0.f, 0.f, 0.f, 0.f};      // anchor h_{t-1}: register-resident

        __syncthreads();   // pairs with service-wave init barrier (sh_x slot 0 staged)

        #pragma unroll 1
        for (int t = 0; t < T_; t++) {
            // ---- 1. relaxed spin: all peers' step t-1 stores are at the coherence point ----
            if (t > 0 && lane == 0) {
                const unsigned target = (unsigned)(SIGS * t);
                while (__hip_atomic_load(myctr, __ATOMIC_RELAXED, __HIP_MEMORY_SCOPE_AGENT) < target)
                    __builtin_amdgcn_s_sleep(1);
            }

            // ---- 2. A-fragments from coherence point: 16 x 16B, one round trip ----
            f16x8 afr[16];
            const f16* abase = hbuf + (size_t)((t & 1) ^ 1) * (B_ * H_)
                             + (size_t)(b0 + mrow) * H_ + quad * 8;
            asm volatile(
                "global_load_dwordx4 %0, %16, off sc0 sc1\n\t"
                "global_load_dwordx4 %1, %16, off offset:64 sc0 sc1\n\t"
                "global_load_dwordx4 %2, %16, off offset:128 sc0 sc1\n\t"
                "global_load_dwordx4 %3, %16, off offset:192 sc0 sc1\n\t"
                "global_load_dwordx4 %4, %16, off offset:256 sc0 sc1\n\t"
                "global_load_dwordx4 %5, %16, off offset:320 sc0 sc1\n\t"
                "global_load_dwordx4 %6, %16, off offset:384 sc0 sc1\n\t"
                "global_load_dwordx4 %7, %16, off offset:448 sc0 sc1\n\t"
                "global_load_dwordx4 %8, %16, off offset:512 sc0 sc1\n\t"
                "global_load_dwordx4 %9, %16, off offset:576 sc0 sc1\n\t"
                "global_load_dwordx4 %10, %16, off offset:640 sc0 sc1\n\t"
                "global_load_dwordx4 %11, %16, off offset:704 sc0 sc1\n\t"
                "global_load_dwordx4 %12, %16, off offset:768 sc0 sc1\n\t"
                "global_load_dwordx4 %13, %16, off offset:832 sc0 sc1\n\t"
                "global_load_dwordx4 %14, %16, off offset:896 sc0 sc1\n\t"
                "global_load_dwordx4 %15, %16, off offset:960 sc0 sc1\n\t"
                "s_waitcnt vmcnt(0)"
                : "=&v"(afr[0]), "=&v"(afr[1]), "=&v"(afr[2]), "=&v"(afr[3]),
                  "=&v"(afr[4]), "=&v"(afr[5]), "=&v"(afr[6]), "=&v"(afr[7]),
                  "=&v"(afr[8]), "=&v"(afr[9]), "=&v"(afr[10]), "=&v"(afr[11]),
                  "=&v"(afr[12]), "=&v"(afr[13]), "=&v"(afr[14]), "=&v"(afr[15])
                : "v"(abase)
                : "memory");

            // ---- 3. MFMA: x-proj init, then K=512 over h. All 3 gates, same lane layout ----
            f16x8 ax0 = *(const f16x8*)&sh_x[t & 1][mrow][quad * 8];
            f16x8 ax1 = *(const f16x8*)&sh_x[t & 1][mrow][32 + quad * 8];
            const f32x4 zero = {0.f, 0.f, 0.f, 0.f};
            f32x4 a_r  = __builtin_amdgcn_mfma_f32_16x16x32_f16(ax0, wx[0][0], zero, 0, 0, 0);
            f32x4 a_z  = __builtin_amdgcn_mfma_f32_16x16x32_f16(ax0, wx[1][0], zero, 0, 0, 0);
            f32x4 a_ni = __builtin_amdgcn_mfma_f32_16x16x32_f16(ax0, wx[2][0], zero, 0, 0, 0);
            a_r  = __builtin_amdgcn_mfma_f32_16x16x32_f16(ax1, wx[0][1], a_r,  0, 0, 0);
            a_z  = __builtin_amdgcn_mfma_f32_16x16x32_f16(ax1, wx[1][1], a_z,  0, 0, 0);
            a_ni = __builtin_amdgcn_mfma_f32_16x16x32_f16(ax1, wx[2][1], a_ni, 0, 0, 0);
            f32x4 a_nh = zero;
            #pragma unroll
            for (int kt = 0; kt < 16; kt++) {
                a_r  = __builtin_amdgcn_mfma_f32_16x16x32_f16(afr[kt], wh[0][kt], a_r,  0, 0, 0);
                a_z  = __builtin_amdgcn_mfma_f32_16x16x32_f16(afr[kt], wh[1][kt], a_z,  0, 0, 0);
                a_nh = __builtin_amdgcn_mfma_f32_16x16x32_f16(afr[kt], wh[2][kt], a_nh, 0, 0, 0);
            }

            __syncthreads();   // sh_x ping-pong fence (service wrote slot (t+1)&1). Off the tail.

            // ---- 4. gates in registers; write-through h stores; drain; signal ----
            float vcon[4];
            #pragma unroll
            for (int r = 0; r < 4; r++) {     // C/D: col=lane&15 (unit), row=quad*4+r (batch)
                float rg = sigmoid_f(a_r[r] + b_r);
                float zg = sigmoid_f(a_z[r] + b_z);
                float ng = tanh_f(a_ni[r] + b_ni + rg * (a_nh[r] + b_nh));
                float hn = (1.f - zg) * ng + zg * hprev[r];
                hprev[r] = hn;
                union { f16 h; unsigned short u; } pk; pk.h = (f16)hn;
                f16* hp = hbuf + (size_t)(t & 1) * (B_ * H_)
                        + (size_t)(b0 + quad * 4 + r) * H_ + HS * j + wv * 16 + mrow;
                unsigned int sval = pk.u;
                asm volatile("global_store_short %0, %1, off sc0 sc1"
                             :: "v"(hp), "v"(sval) : "memory");
                vcon[r] = hn * vw_u;
            }
            asm volatile("s_waitcnt vmcnt(0)" ::: "memory");   // own stores at coherence point
            if (lane == 0)
                __hip_atomic_fetch_add(myctr, 1u, __ATOMIC_RELAXED, __HIP_MEMORY_SCOPE_AGENT);

            // ---- 5. value head (hidden behind peers' latency) ----
            #pragma unroll
            for (int r = 0; r < 4; r++) {
                float s = vcon[r];
                s += __shfl_xor(s, 1); s += __shfl_xor(s, 2);
                s += __shfl_xor(s, 4); s += __shfl_xor(s, 8);
                vcon[r] = s;   // sum over this wave's 16 units, batch row quad*4+r
            }
            if ((lane & 15) == 0) {
                const int sl = j * NMW + wv;
                if (use_part) {
                    float* pp = part + (size_t)sl * (T_ * B_) + (size_t)t * B_ + b0 + quad * 4;
                    *(float4*)pp = make_float4(vcon[0], vcon[1], vcon[2], vcon[3]);
                } else {
                    #pragma unroll
                    for (int r = 0; r < 4; r++)
                        atomicAdd(&Vout[(size_t)t * B_ + b0 + quad * 4 + r],
                                  vcon[r] + (sl == 0 ? bias0 : 0.f) * (r == r ? 1.f : 1.f) * ((sl == 0) ? 1.f : 1.f) + 0.f);
                }
            }
        }
    } else {
        // ================= service wave: X prefetch (HBM latency off-path) =================
        const int bb  = lane >> 2;
        const int seg = (lane & 3) * 16;
        {   // stage X_0 into slot 0
            const float* xs = X + (size_t)(b0 + bb) * I_ + seg;
            const float4 x0 = *(const float4*)(xs + 0),  x1 = *(const float4*)(xs + 4);
            const float4 x2 = *(const float4*)(xs + 8),  x3 = *(const float4*)(xs + 12);
            f16* dst = &sh_x[0][bb][seg];
            f16x8 p0 = {(f16)x0.x,(f16)x0.y,(f16)x0.z,(f16)x0.w,(f16)x1.x,(f16)x1.y,(f16)x1.z,(f16)x1.w};
            f16x8 p1 = {(f16)x2.x,(f16)x2.y,(f16)x2.z,(f16)x2.w,(f16)x3.x,(f16)x3.y,(f16)x3.z,(f16)x3.w};
            *(f16x8*)dst = p0; *(f16x8*)(dst + 8) = p1;
        }
        __syncthreads();   // init barrier

        #pragma unroll 1
        for (int t = 0; t < T_; t++) {
            if (t + 1 < T_) {
                const float* xs = X + (size_t)(t + 1) * (B_ * I_) + (size_t)(b0 + bb) * I_ + seg;
                const float4 x0 = *(const float4*)(xs + 0),  x1 = *(const float4*)(xs + 4);
                const float4 x2 = *(const float4*)(xs + 8),  x3 = *(const float4*)(xs + 12);
                f16* dst = &sh_x[(t + 1) & 1][bb][seg];
                f16x8 p0 = {(f16)x0.x,(f16)x0.y,(f16)x0.z,(f16)x0.w,(f16)x1.x,(f16)x1.y,(f16)x1.z,(f16)x1.w};
                f16x8 p1 = {(f16)x2.x,(f16)x2.y,(f16)x2.z,(f16)x2.w,(f16)x3.x,(f16)x3.y,(f16)x3.z,(f16)x3.w};
                *(f16x8*)dst = p0; *(f16x8*)(dst + 8) = p1;
            }
            __syncthreads();   // one barrier per step, same count as MFMA waves
        }
    }
}

__global__ __launch_bounds__(256) void value_reduce(
    const float* __restrict__ part, const float* __restrict__ bias,
    float* __restrict__ Vout)
{
    const int i = blockIdx.x * 256 + threadIdx.x;   // i < T_*B_
    float s = bias[0];
    #pragma unroll
    for (int sl = 0; sl < NSL; sl++) s += part[(size_t)sl * (T_ * B_) + i];
    Vout[i] = s;
}

extern "C" void kernel_launch(void* const* d_in, const int* in_sizes, int n_in,
                              void* d_out, int out_size, void* d_ws, size_t ws_size,
                              hipStream_t stream) {
    const float* X    = (const float*)d_in[0];
    const float* Wih  = (const float*)d_in[1];
    const float* Whh  = (const float*)d_in[2];
    const float* bih  = (const float*)d_in[3];
    const float* bhh  = (const float*)d_in[4];
    const float* vw   = (const float*)d_in[5];
    const float* bias = (const float*)d_in[6];
    float* Vout = (float*)d_out;

    f16* hbuf = (f16*)d_ws;
    const size_t hbytes   = (size_t)2 * B_ * H_ * sizeof(f16);            // 512 KB
    const size_t ctrbytes = (size_t)NBG * CTR_STRIDE * sizeof(unsigned);  // 2 KB
    unsigned int* ctr = (unsigned int*)((char*)d_ws + hbytes);
    float* part = (float*)((char*)d_ws + hbytes + ctrbytes);
    const size_t partbytes = (size_t)NSL * T_ * B_ * sizeof(float);       // 16.8 MB
    const int use_part = (ws_size >= hbytes + ctrbytes + partbytes) ? 1 : 0;

    hipMemsetAsync(d_ws, 0, hbytes + ctrbytes, stream);
    if (!use_part)
        hipMemsetAsync(d_out, 0, (size_t)out_size * sizeof(float), stream);

    gru_persistent<<<256, BLOCK, 0, stream>>>(X, Wih, Whh, bih, bhh, vw, bias,
                                              Vout, hbuf, ctr, part, use_part);
    if (use_part)
        value_reduce<<<(T_ * B_) / 256, 256, 0, stream>>>(part, bias, Vout);
}